// Round 1
// baseline (1442.812 us; speedup 1.0000x reference)
//
#include <hip/hip_runtime.h>
#include <hip/hip_bf16.h>

// Problem constants (fixed by the reference)
#define EPSF 1e-8f
constexpr int M_ = 8, N_ = 100000, D_ = 256, H_ = 256;

typedef short  short8  __attribute__((ext_vector_type(8)));   // bf16x8 MFMA frag (4 VGPRs)
typedef short  short4_ __attribute__((ext_vector_type(4)));
typedef float  float4_ __attribute__((ext_vector_type(4)));

__device__ __forceinline__ short bf16_rn(float x) {
  union { float f; unsigned u; } v; v.f = x;
  unsigned r = v.u + 0x7FFFu + ((v.u >> 16) & 1u);   // round-to-nearest-even
  return (short)(r >> 16);
}

// LDS strides (elements):
//   xb (bf16): 264  -> row byte-stride 528; A-frag b128 reads spread 8 lanes/bank-quad (optimal)
//   xf (f32) : 257  -> (r + j) % 32 banks, conflict-free scalar access
//   tg (f32) : 260  -> 16B-aligned float4 stores
#define XB_S 264
#define XF_S 257
#define TG_S 260

__global__ __launch_bounds__(256, 2) void fused_hete(
    const int* __restrict__ nodes, const float* __restrict__ homo,
    const float* __restrict__ W, const float* __restrict__ bias,
    const float* __restrict__ oute, float* __restrict__ out)
{
  __shared__ __align__(16) short xb[16 * XB_S];
  __shared__ __align__(16) float xf[16 * XF_S];
  __shared__ __align__(16) float tg[2 * TG_S];
  __shared__ float rnum[4][16];
  __shared__ float rhn[4][16];
  __shared__ float cos_s[16];
  __shared__ float att_s[2][8];
  __shared__ float tn_s[2];

  const int t    = threadIdx.x;
  const int wave = t >> 6, lane = t & 63;
  const int quad = lane >> 4, l16 = lane & 15;

  // ---- Preload W as B-fragments in registers (per wave: cols wave*64 .. +63) ----
  // B-frag (16x16x32): lane holds B[k][col], col = lane&15, k = quad*8 + j ; B = W^T so
  // B[k][col] = W[colglobal][k]  -> 8 contiguous floats of row colglobal at k0*32+quad*8.
  short8 wf[4][8];
  float  bcol[4];
  #pragma unroll
  for (int tt = 0; tt < 4; ++tt) {
    const int col = wave * 64 + tt * 16 + l16;
    bcol[tt] = bias[col];
    #pragma unroll
    for (int k0 = 0; k0 < 8; ++k0) {
      const float* wp = W + (size_t)col * D_ + k0 * 32 + quad * 8;
      short8 f;
      #pragma unroll
      for (int j = 0; j < 8; ++j) f[j] = bf16_rn(wp[j]);
      wf[tt][k0] = f;
    }
  }

  for (int pair = blockIdx.x; pair < N_ / 2; pair += gridDim.x) {
    const int n0 = pair * 2;

    // ---- Stage X rows (16 = 2n x 8m) into LDS (bf16 for MFMA + f32 for epilogue) ----
    {
      const int r = t >> 4, c = t & 15;          // 16 threads per row, coalesced 256B
      const int m = r & 7, ln = r >> 3;          // row r = ln*8 + m
      const float* src = homo + ((size_t)m * N_ + (n0 + ln)) * D_;
      #pragma unroll
      for (int i = 0; i < 4; ++i) {
        const int d = i * 64 + c * 4;
        const float4 v = *(const float4*)(src + d);
        float* xfr = &xf[r * XF_S + d];
        xfr[0] = v.x; xfr[1] = v.y; xfr[2] = v.z; xfr[3] = v.w;
        short4_ s;
        s[0] = bf16_rn(v.x); s[1] = bf16_rn(v.y); s[2] = bf16_rn(v.z); s[3] = bf16_rn(v.w);
        *(short4_*)&xb[r * XB_S + d] = s;        // byte off = 2*(264r+d), d%4==0 -> 8B aligned
      }
      // target embeddings (gather) + their norms (waves 0,1 fully active under t<128)
      if (t < 128) {
        const int ln2 = t >> 6, c2 = t & 63;
        const int node = nodes[n0 + ln2];
        const float4 v = *(const float4*)(oute + (size_t)node * H_ + c2 * 4);
        float* tp = &tg[ln2 * TG_S + c2 * 4];
        tp[0] = v.x; tp[1] = v.y; tp[2] = v.z; tp[3] = v.w;
        float sq = v.x * v.x + v.y * v.y + v.z * v.z + v.w * v.w;
        #pragma unroll
        for (int off = 32; off; off >>= 1) sq += __shfl_down(sq, off);
        if (c2 == 0) tn_s[ln2] = fmaxf(sqrtf(sq), EPSF);
      }
    }
    __syncthreads();

    // ---- MFMA: hidden tile 16 rows x 64 cols per wave, K = 256 ----
    float4_ acc[4] = {};
    #pragma unroll
    for (int k0 = 0; k0 < 8; ++k0) {
      // A-frag: A[m=lane&15][k=quad*8+j] -> row l16, 8 contiguous bf16 at k0*32+quad*8
      const short8 af = *(const short8*)&xb[l16 * XB_S + k0 * 32 + quad * 8];
      #pragma unroll
      for (int tt = 0; tt < 4; ++tt)
        acc[tt] = __builtin_amdgcn_mfma_f32_16x16x32_bf16(af, wf[tt][k0], acc[tt], 0, 0, 0);
    }

    // ---- Epilogue: tanh, partial dot with tgt and ||hidden||^2 ----
    // C-layout: col = lane&15 (+tile), row = quad*4 + e  ->  quad's 4 rows share n = quad>>1
    const int lnq = quad >> 1;
    float nump[4] = {0.f, 0.f, 0.f, 0.f}, hnp[4] = {0.f, 0.f, 0.f, 0.f};
    #pragma unroll
    for (int tt = 0; tt < 4; ++tt) {
      const float tv = tg[lnq * TG_S + wave * 64 + tt * 16 + l16];
      #pragma unroll
      for (int e = 0; e < 4; ++e) {
        const float h = tanhf(acc[tt][e] + bcol[tt]);
        nump[e] += h * tv;
        hnp[e]  += h * h;
      }
    }
    #pragma unroll
    for (int off = 1; off < 16; off <<= 1) {   // reduce across the 16 lanes of each quad
      #pragma unroll
      for (int e = 0; e < 4; ++e) {
        nump[e] += __shfl_xor(nump[e], off);
        hnp[e]  += __shfl_xor(hnp[e], off);
      }
    }
    if (l16 == 0) {
      #pragma unroll
      for (int e = 0; e < 4; ++e) {
        rnum[wave][quad * 4 + e] = nump[e];
        rhn[wave][quad * 4 + e]  = hnp[e];
      }
    }
    __syncthreads();

    // ---- cosine sims (16 rows) ----
    if (t < 16) {
      const float nm = rnum[0][t] + rnum[1][t] + rnum[2][t] + rnum[3][t];
      const float hq = rhn[0][t] + rhn[1][t] + rhn[2][t] + rhn[3][t];
      const float hn = fmaxf(sqrtf(hq), EPSF);
      cos_s[t] = nm / (hn * tn_s[t >> 3]);
    }
    __syncthreads();

    // ---- softmax over the 8 meta-paths, per n ----
    if (t < 2) {
      float mx = cos_s[t * 8];
      #pragma unroll
      for (int m = 1; m < 8; ++m) mx = fmaxf(mx, cos_s[t * 8 + m]);
      float s = 0.f, ex[8];
      #pragma unroll
      for (int m = 0; m < 8; ++m) { ex[m] = expf(cos_s[t * 8 + m] - mx); s += ex[m]; }
      const float inv = 1.f / s;
      #pragma unroll
      for (int m = 0; m < 8; ++m) att_s[t][m] = ex[m] * inv;
    }
    __syncthreads();

    // ---- final: out[n][d] = sum_m att[m] * x_fp32[m][n][d] ----
    {
      const int ln = t >> 7, j = t & 127;
      float s0 = 0.f, s1 = 0.f;
      #pragma unroll
      for (int m = 0; m < 8; ++m) {
        const float a = att_s[ln][m];
        s0 += a * xf[(ln * 8 + m) * XF_S + j];
        s1 += a * xf[(ln * 8 + m) * XF_S + j + 128];
      }
      float* op = out + (size_t)(n0 + ln) * D_;
      op[j] = s0; op[j + 128] = s1;
    }
    __syncthreads();   // protect LDS before next iteration's staging
  }
}

extern "C" void kernel_launch(void* const* d_in, const int* in_sizes, int n_in,
                              void* d_out, int out_size, void* d_ws, size_t ws_size,
                              hipStream_t stream) {
  const int*   nodes = (const int*)d_in[0];
  const float* homo  = (const float*)d_in[1];
  const float* W     = (const float*)d_in[2];
  const float* b     = (const float*)d_in[3];
  const float* oute  = (const float*)d_in[4];
  float* out = (float*)d_out;
  // 512 blocks = 2 blocks/CU at __launch_bounds__(256,2); grid-stride over 50000 n-pairs
  fused_hete<<<dim3(512), dim3(256), 0, stream>>>(nodes, homo, W, b, oute, out);
}